// Round 1
// baseline (1712.859 us; speedup 1.0000x reference)
//
#include <hip/hip_runtime.h>

// ---------------------------------------------------------------------------
// 2-layer GCN + link-prediction dot products.
// Key restructure vs reference: aggregation is linear, so layer-2 does
// Agg(relu(z1)) first (16-dim scatter) then @W2 (+b2) — 4x less atomic traffic
// than scattering the 64-dim projected features.
//
// z1 = relu(dinv * (scatter(hs) + hs) + b1),  hs = (x@W1) * dinv
// z2 = (dinv * (scatter(gs) + gs)) @ W2 + b2, gs = z1 * dinv
// logits[e] = dot(z2[a], z2[b])
// ---------------------------------------------------------------------------

__global__ void deg_kernel(const int* __restrict__ dst, int E, float* __restrict__ deg) {
    int i = blockIdx.x * blockDim.x + threadIdx.x;
    if (i < E) atomicAdd(&deg[dst[i]], 1.0f);
}

__global__ void dinv_kernel(float* __restrict__ deg, int n) {
    int i = blockIdx.x * blockDim.x + threadIdx.x;
    if (i < n) deg[i] = rsqrtf(deg[i] + 1.0f);   // +1: self loop
}

// hs[row][c] = (sum_k x[row][k] * W1[k][c]) * dinv[row],  c in [0,16)
__global__ void gemm1_kernel(const float* __restrict__ x, const float* __restrict__ W1,
                             const float* __restrict__ dinv, float* __restrict__ hs, int n) {
    __shared__ float4 sW[1024];                   // 256x16 floats
    const float4* W14 = (const float4*)W1;
    for (int i = threadIdx.x; i < 1024; i += 256) sW[i] = W14[i];
    __syncthreads();
    int row = blockIdx.x * 256 + threadIdx.x;
    if (row >= n) return;
    const float4* x4 = (const float4*)(x + (size_t)row * 256);
    float4 a0 = {0,0,0,0}, a1 = {0,0,0,0}, a2 = {0,0,0,0}, a3 = {0,0,0,0};
    for (int k4 = 0; k4 < 64; ++k4) {
        float4 xv = x4[k4];
        #pragma unroll
        for (int j = 0; j < 4; ++j) {
            float xk = (j == 0) ? xv.x : (j == 1) ? xv.y : (j == 2) ? xv.z : xv.w;
            int k = (k4 << 2) + j;
            float4 w0 = sW[k * 4 + 0];
            float4 w1 = sW[k * 4 + 1];
            float4 w2 = sW[k * 4 + 2];
            float4 w3 = sW[k * 4 + 3];
            a0.x += xk * w0.x; a0.y += xk * w0.y; a0.z += xk * w0.z; a0.w += xk * w0.w;
            a1.x += xk * w1.x; a1.y += xk * w1.y; a1.z += xk * w1.z; a1.w += xk * w1.w;
            a2.x += xk * w2.x; a2.y += xk * w2.y; a2.z += xk * w2.z; a2.w += xk * w2.w;
            a3.x += xk * w3.x; a3.y += xk * w3.y; a3.z += xk * w3.z; a3.w += xk * w3.w;
        }
    }
    float di = dinv[row];
    float4* o = (float4*)(hs + (size_t)row * 16);
    a0.x *= di; a0.y *= di; a0.z *= di; a0.w *= di;
    a1.x *= di; a1.y *= di; a1.z *= di; a1.w *= di;
    a2.x *= di; a2.y *= di; a2.z *= di; a2.w *= di;
    a3.x *= di; a3.y *= di; a3.z *= di; a3.w *= di;
    o[0] = a0; o[1] = a1; o[2] = a2; o[3] = a3;
}

// 4 threads per edge; each gathers one float4 of hs[src] and does 4 atomicAdds
// into acc[dst].
__global__ void scatter_kernel(const int* __restrict__ src, const int* __restrict__ dst, int E,
                               const float4* __restrict__ hs4, float* __restrict__ acc) {
    int t = blockIdx.x * blockDim.x + threadIdx.x;
    int e = t >> 2, q = t & 3;
    if (e >= E) return;
    int s = src[e], d = dst[e];
    float4 v = hs4[s * 4 + q];
    float* a = acc + (size_t)d * 16 + q * 4;
    atomicAdd(a + 0, v.x);
    atomicAdd(a + 1, v.y);
    atomicAdd(a + 2, v.z);
    atomicAdd(a + 3, v.w);
}

// hs <- relu(dinv*(acc+hs)+b1) * dinv   (in place; result is gs for layer 2)
__global__ void finalize1_kernel(float4* __restrict__ hs4, const float4* __restrict__ acc4,
                                 const float* __restrict__ dinv, const float* __restrict__ b1,
                                 int n) {
    int t = blockIdx.x * blockDim.x + threadIdx.x;
    int v = t >> 2, q = t & 3;
    if (v >= n) return;
    float di = dinv[v];
    float4 h = hs4[v * 4 + q];
    float4 a = acc4[v * 4 + q];
    float4 b = ((const float4*)b1)[q];
    float4 z;
    z.x = fmaxf(di * (a.x + h.x) + b.x, 0.0f) * di;
    z.y = fmaxf(di * (a.y + h.y) + b.y, 0.0f) * di;
    z.z = fmaxf(di * (a.z + h.z) + b.z, 0.0f) * di;
    z.w = fmaxf(di * (a.w + h.w) + b.w, 0.0f) * di;
    hs4[v * 4 + q] = z;
}

// z2[v][:] = (dinv[v]*(acc[v][:]+gs[v][:])) @ W2 + b2 ; 4 threads per row,
// each produces 16 of the 64 outputs.
__global__ void gemm2_kernel(const float* __restrict__ gs, const float* __restrict__ acc,
                             const float* __restrict__ dinv, const float* __restrict__ W2,
                             const float* __restrict__ b2, float* __restrict__ z2, int n) {
    __shared__ float4 sW[256];                    // 16x64 floats
    __shared__ float sb[64];
    for (int i = threadIdx.x; i < 256; i += 256) sW[i] = ((const float4*)W2)[i];
    if (threadIdx.x < 64) sb[threadIdx.x] = b2[threadIdx.x];
    __syncthreads();
    int t = blockIdx.x * 256 + threadIdx.x;
    int v = t >> 2, jq = t & 3;
    if (v >= n) return;
    float di = dinv[v];
    const float4* g4 = (const float4*)(gs + (size_t)v * 16);
    const float4* a4 = (const float4*)(acc + (size_t)v * 16);
    float tc[16];
    #pragma unroll
    for (int q = 0; q < 4; ++q) {
        float4 g = g4[q], a = a4[q];
        tc[q * 4 + 0] = di * (a.x + g.x);
        tc[q * 4 + 1] = di * (a.y + g.y);
        tc[q * 4 + 2] = di * (a.z + g.z);
        tc[q * 4 + 3] = di * (a.w + g.w);
    }
    float4 o0 = {0,0,0,0}, o1 = {0,0,0,0}, o2 = {0,0,0,0}, o3 = {0,0,0,0};
    #pragma unroll
    for (int c = 0; c < 16; ++c) {
        float tcc = tc[c];
        float4 w0 = sW[c * 16 + jq * 4 + 0];
        float4 w1 = sW[c * 16 + jq * 4 + 1];
        float4 w2 = sW[c * 16 + jq * 4 + 2];
        float4 w3 = sW[c * 16 + jq * 4 + 3];
        o0.x += tcc * w0.x; o0.y += tcc * w0.y; o0.z += tcc * w0.z; o0.w += tcc * w0.w;
        o1.x += tcc * w1.x; o1.y += tcc * w1.y; o1.z += tcc * w1.z; o1.w += tcc * w1.w;
        o2.x += tcc * w2.x; o2.y += tcc * w2.y; o2.z += tcc * w2.z; o2.w += tcc * w2.w;
        o3.x += tcc * w3.x; o3.y += tcc * w3.y; o3.z += tcc * w3.z; o3.w += tcc * w3.w;
    }
    const float4* sb4 = (const float4*)sb;
    float4 b0 = sb4[jq * 4 + 0], b1v = sb4[jq * 4 + 1], b2v = sb4[jq * 4 + 2], b3 = sb4[jq * 4 + 3];
    o0.x += b0.x;  o0.y += b0.y;  o0.z += b0.z;  o0.w += b0.w;
    o1.x += b1v.x; o1.y += b1v.y; o1.z += b1v.z; o1.w += b1v.w;
    o2.x += b2v.x; o2.y += b2v.y; o2.z += b2v.z; o2.w += b2v.w;
    o3.x += b3.x;  o3.y += b3.y;  o3.z += b3.z;  o3.w += b3.w;
    float4* o = (float4*)(z2 + (size_t)v * 64 + jq * 16);
    o[0] = o0; o[1] = o1; o[2] = o2; o[3] = o3;
}

// 16 lanes per edge: lane reads one float4 from each endpoint row, 4 MACs,
// then 16-lane butterfly reduce.
__global__ void edge_dot_kernel(const int* __restrict__ ia, const int* __restrict__ ib, int m,
                                const float4* __restrict__ z24, float* __restrict__ out) {
    int t = blockIdx.x * blockDim.x + threadIdx.x;
    int e = t >> 4, l = t & 15;
    if (e >= m) return;
    int a = ia[e], b = ib[e];
    float4 va = z24[(size_t)a * 16 + l];
    float4 vb = z24[(size_t)b * 16 + l];
    float p = va.x * vb.x + va.y * vb.y + va.z * vb.z + va.w * vb.w;
    p += __shfl_xor(p, 1);
    p += __shfl_xor(p, 2);
    p += __shfl_xor(p, 4);
    p += __shfl_xor(p, 8);
    if (l == 0) out[e] = p;
}

extern "C" void kernel_launch(void* const* d_in, const int* in_sizes, int n_in,
                              void* d_out, int out_size, void* d_ws, size_t ws_size,
                              hipStream_t stream) {
    const float* x    = (const float*)d_in[0];
    const int*   tei  = (const int*)d_in[1];
    const int*   tpos = (const int*)d_in[2];
    const int*   tneg = (const int*)d_in[3];
    const float* W1   = (const float*)d_in[4];
    const float* b1   = (const float*)d_in[5];
    const float* W2   = (const float*)d_in[6];
    const float* b2   = (const float*)d_in[7];
    float* out = (float*)d_out;

    int n  = in_sizes[0] / 256;   // 100000 nodes
    int E  = in_sizes[1] / 2;     // 3.2M train edges
    int ET = in_sizes[2] / 2;     // 500K test edges each

    float* ws   = (float*)d_ws;
    float* dinv = ws;                         // n floats (holds deg, then rsqrt)
    float* acc  = ws + n;                     // 16n floats (contiguous with dinv for one memset)
    float* hs   = acc + (size_t)16 * n;       // 16n floats
    float* z2   = hs + (size_t)16 * n;        // 64n floats

    // zero deg + acc in one shot
    hipMemsetAsync(dinv, 0, (size_t)(17 * (size_t)n) * sizeof(float), stream);

    deg_kernel<<<(E + 255) / 256, 256, 0, stream>>>(tei + E, E, dinv);
    dinv_kernel<<<(n + 255) / 256, 256, 0, stream>>>(dinv, n);
    gemm1_kernel<<<(n + 255) / 256, 256, 0, stream>>>(x, W1, dinv, hs, n);
    scatter_kernel<<<(4 * E + 255) / 256, 256, 0, stream>>>(tei, tei + E, E,
                                                            (const float4*)hs, acc);
    finalize1_kernel<<<(4 * n + 255) / 256, 256, 0, stream>>>((float4*)hs, (const float4*)acc,
                                                              dinv, b1, n);
    hipMemsetAsync(acc, 0, (size_t)16 * n * sizeof(float), stream);
    scatter_kernel<<<(4 * E + 255) / 256, 256, 0, stream>>>(tei, tei + E, E,
                                                            (const float4*)hs, acc);
    gemm2_kernel<<<(4 * n + 255) / 256, 256, 0, stream>>>(hs, acc, dinv, W2, b2, z2, n);
    edge_dot_kernel<<<(16 * ET + 255) / 256, 256, 0, stream>>>(tpos, tpos + ET, ET,
                                                               (const float4*)z2, out);
    edge_dot_kernel<<<(16 * ET + 255) / 256, 256, 0, stream>>>(tneg, tneg + ET, ET,
                                                               (const float4*)z2, out + ET);
}

// Round 2
// 779.354 us; speedup vs baseline: 2.1978x; 2.1978x over previous
//
#include <hip/hip_runtime.h>

// ---------------------------------------------------------------------------
// 2-layer GCN + link-prediction dot products.
// R2: replaced 51.2M-float-atomic scatter (800 MB HBM RMW writes, 2x636us)
// with CSR build (int atomics, built once, used for both layers) + atomic-free
// per-node gather aggregation. Finalize/scale fused into gather epilogues.
//
// hs = (x@W1) * dinv
// gs = relu(dinv*(gather(hs)+hs)+b1) * dinv
// u  = dinv*(gather(gs)+gs)
// z2 = u @ W2 + b2
// logits[e] = dot(z2[a], z2[b])
// ---------------------------------------------------------------------------

__global__ void hist_kernel(const int* __restrict__ dst, int E, int* __restrict__ counts) {
    int i = blockIdx.x * blockDim.x + threadIdx.x;
    if (i < E) atomicAdd(&counts[dst[i]], 1);
}

// per-256-block sums of counts
__global__ void blocksum_kernel(const int* __restrict__ counts, int n, int* __restrict__ bsum) {
    __shared__ int s[256];
    int i = blockIdx.x * 256 + threadIdx.x;
    int v = (i < n) ? counts[i] : 0;
    s[threadIdx.x] = v;
    __syncthreads();
    for (int off = 128; off > 0; off >>= 1) {
        if (threadIdx.x < off) s[threadIdx.x] += s[threadIdx.x + off];
        __syncthreads();
    }
    if (threadIdx.x == 0) bsum[blockIdx.x] = s[0];
}

// single-block exclusive scan of bsum[0..nb) (nb <= 512)
__global__ void scanb_kernel(int* __restrict__ bsum, int nb) {
    __shared__ int s[512];
    int t = threadIdx.x;
    int v = (t < nb) ? bsum[t] : 0;
    s[t] = v;
    __syncthreads();
    for (int off = 1; off < 512; off <<= 1) {
        int x = (t >= off) ? s[t - off] : 0;
        __syncthreads();
        s[t] += x;
        __syncthreads();
    }
    if (t < nb) bsum[t] = s[t] - v;   // exclusive
}

// exclusive scan within each 256-block + block offset; write rowptr, cursor, dinv
__global__ void scatter_prep_kernel(const int* __restrict__ counts, const int* __restrict__ bsum,
                                    int n, int* __restrict__ rowptr, int* __restrict__ cursor,
                                    float* __restrict__ dinv) {
    __shared__ int s[256];
    int t = threadIdx.x;
    int i = blockIdx.x * 256 + t;
    int c = (i < n) ? counts[i] : 0;
    s[t] = c;
    __syncthreads();
    for (int off = 1; off < 256; off <<= 1) {
        int x = (t >= off) ? s[t - off] : 0;
        __syncthreads();
        s[t] += x;
        __syncthreads();
    }
    if (i < n) {
        int pre = s[t] - c + bsum[blockIdx.x];
        rowptr[i] = pre;
        cursor[i] = pre;
        dinv[i] = rsqrtf((float)c + 1.0f);   // +1: self loop
    }
}

__global__ void fill_kernel(const int* __restrict__ src, const int* __restrict__ dst, int E,
                            int* __restrict__ cursor, int* __restrict__ eidx) {
    int e = blockIdx.x * blockDim.x + threadIdx.x;
    if (e >= E) return;
    int slot = atomicAdd(&cursor[dst[e]], 1);
    eidx[slot] = src[e];
}

// hs[row][c] = (sum_k x[row][k] * W1[k][c]) * dinv[row],  c in [0,16)
__global__ void gemm1_kernel(const float* __restrict__ x, const float* __restrict__ W1,
                             const float* __restrict__ dinv, float* __restrict__ hs, int n) {
    __shared__ float4 sW[1024];                   // 256x16 floats
    const float4* W14 = (const float4*)W1;
    for (int i = threadIdx.x; i < 1024; i += 256) sW[i] = W14[i];
    __syncthreads();
    int row = blockIdx.x * 256 + threadIdx.x;
    if (row >= n) return;
    const float4* x4 = (const float4*)(x + (size_t)row * 256);
    float4 a0 = {0,0,0,0}, a1 = {0,0,0,0}, a2 = {0,0,0,0}, a3 = {0,0,0,0};
    for (int k4 = 0; k4 < 64; ++k4) {
        float4 xv = x4[k4];
        #pragma unroll
        for (int j = 0; j < 4; ++j) {
            float xk = (j == 0) ? xv.x : (j == 1) ? xv.y : (j == 2) ? xv.z : xv.w;
            int k = (k4 << 2) + j;
            float4 w0 = sW[k * 4 + 0];
            float4 w1 = sW[k * 4 + 1];
            float4 w2 = sW[k * 4 + 2];
            float4 w3 = sW[k * 4 + 3];
            a0.x += xk * w0.x; a0.y += xk * w0.y; a0.z += xk * w0.z; a0.w += xk * w0.w;
            a1.x += xk * w1.x; a1.y += xk * w1.y; a1.z += xk * w1.z; a1.w += xk * w1.w;
            a2.x += xk * w2.x; a2.y += xk * w2.y; a2.z += xk * w2.z; a2.w += xk * w2.w;
            a3.x += xk * w3.x; a3.y += xk * w3.y; a3.z += xk * w3.z; a3.w += xk * w3.w;
        }
    }
    float di = dinv[row];
    float4* o = (float4*)(hs + (size_t)row * 16);
    a0.x *= di; a0.y *= di; a0.z *= di; a0.w *= di;
    a1.x *= di; a1.y *= di; a1.z *= di; a1.w *= di;
    a2.x *= di; a2.y *= di; a2.z *= di; a2.w *= di;
    a3.x *= di; a3.y *= di; a3.z *= di; a3.w *= di;
    o[0] = a0; o[1] = a1; o[2] = a2; o[3] = a3;
}

// layer-1 aggregate: 4 threads per node, each owns one float4 of the 16 feats.
// gs[v] = relu(dinv*(sum_incoming hs[src] + hs[v]) + b1) * dinv
__global__ void agg1_kernel(const int* __restrict__ rowptr, const int* __restrict__ counts,
                            const int* __restrict__ eidx, const float4* __restrict__ hs4,
                            const float* __restrict__ dinv, const float* __restrict__ b1,
                            float4* __restrict__ gs4, int n) {
    int t = blockIdx.x * blockDim.x + threadIdx.x;
    int v = t >> 2, q = t & 3;
    if (v >= n) return;
    int start = rowptr[v], cnt = counts[v];
    float4 s = {0, 0, 0, 0};
    for (int i = 0; i < cnt; ++i) {
        int sv = eidx[start + i];
        float4 h = hs4[(size_t)sv * 4 + q];
        s.x += h.x; s.y += h.y; s.z += h.z; s.w += h.w;
    }
    float di = dinv[v];
    float4 h = hs4[(size_t)v * 4 + q];
    float4 b = ((const float4*)b1)[q];
    float4 z;
    z.x = fmaxf(di * (s.x + h.x) + b.x, 0.0f) * di;
    z.y = fmaxf(di * (s.y + h.y) + b.y, 0.0f) * di;
    z.z = fmaxf(di * (s.z + h.z) + b.z, 0.0f) * di;
    z.w = fmaxf(di * (s.w + h.w) + b.w, 0.0f) * di;
    gs4[(size_t)v * 4 + q] = z;
}

// layer-2 aggregate: u[v] = dinv*(sum_incoming gs[src] + gs[v])
__global__ void agg2_kernel(const int* __restrict__ rowptr, const int* __restrict__ counts,
                            const int* __restrict__ eidx, const float4* __restrict__ gs4,
                            const float* __restrict__ dinv, float4* __restrict__ u4, int n) {
    int t = blockIdx.x * blockDim.x + threadIdx.x;
    int v = t >> 2, q = t & 3;
    if (v >= n) return;
    int start = rowptr[v], cnt = counts[v];
    float4 s = {0, 0, 0, 0};
    for (int i = 0; i < cnt; ++i) {
        int sv = eidx[start + i];
        float4 g = gs4[(size_t)sv * 4 + q];
        s.x += g.x; s.y += g.y; s.z += g.z; s.w += g.w;
    }
    float di = dinv[v];
    float4 g = gs4[(size_t)v * 4 + q];
    float4 u;
    u.x = di * (s.x + g.x);
    u.y = di * (s.y + g.y);
    u.z = di * (s.z + g.z);
    u.w = di * (s.w + g.w);
    u4[(size_t)v * 4 + q] = u;
}

// z2[v][:] = u[v][:] @ W2 + b2 ; 4 threads per row, each makes 16 of 64 outputs
__global__ void gemm2_kernel(const float* __restrict__ u, const float* __restrict__ W2,
                             const float* __restrict__ b2, float* __restrict__ z2, int n) {
    __shared__ float4 sW[256];                    // 16x64 floats
    __shared__ float sb[64];
    for (int i = threadIdx.x; i < 256; i += 256) sW[i] = ((const float4*)W2)[i];
    if (threadIdx.x < 64) sb[threadIdx.x] = b2[threadIdx.x];
    __syncthreads();
    int t = blockIdx.x * 256 + threadIdx.x;
    int v = t >> 2, jq = t & 3;
    if (v >= n) return;
    const float4* uu4 = (const float4*)(u + (size_t)v * 16);
    float tc[16];
    #pragma unroll
    for (int q = 0; q < 4; ++q) {
        float4 g = uu4[q];
        tc[q * 4 + 0] = g.x;
        tc[q * 4 + 1] = g.y;
        tc[q * 4 + 2] = g.z;
        tc[q * 4 + 3] = g.w;
    }
    float4 o0 = {0,0,0,0}, o1 = {0,0,0,0}, o2 = {0,0,0,0}, o3 = {0,0,0,0};
    #pragma unroll
    for (int c = 0; c < 16; ++c) {
        float tcc = tc[c];
        float4 w0 = sW[c * 16 + jq * 4 + 0];
        float4 w1 = sW[c * 16 + jq * 4 + 1];
        float4 w2 = sW[c * 16 + jq * 4 + 2];
        float4 w3 = sW[c * 16 + jq * 4 + 3];
        o0.x += tcc * w0.x; o0.y += tcc * w0.y; o0.z += tcc * w0.z; o0.w += tcc * w0.w;
        o1.x += tcc * w1.x; o1.y += tcc * w1.y; o1.z += tcc * w1.z; o1.w += tcc * w1.w;
        o2.x += tcc * w2.x; o2.y += tcc * w2.y; o2.z += tcc * w2.z; o2.w += tcc * w2.w;
        o3.x += tcc * w3.x; o3.y += tcc * w3.y; o3.z += tcc * w3.z; o3.w += tcc * w3.w;
    }
    const float4* sb4 = (const float4*)sb;
    float4 b0 = sb4[jq * 4 + 0], b1v = sb4[jq * 4 + 1], b2v = sb4[jq * 4 + 2], b3 = sb4[jq * 4 + 3];
    o0.x += b0.x;  o0.y += b0.y;  o0.z += b0.z;  o0.w += b0.w;
    o1.x += b1v.x; o1.y += b1v.y; o1.z += b1v.z; o1.w += b1v.w;
    o2.x += b2v.x; o2.y += b2v.y; o2.z += b2v.z; o2.w += b2v.w;
    o3.x += b3.x;  o3.y += b3.y;  o3.z += b3.z;  o3.w += b3.w;
    float4* o = (float4*)(z2 + (size_t)v * 64 + jq * 16);
    o[0] = o0; o[1] = o1; o[2] = o2; o[3] = o3;
}

// 16 lanes per edge: lane reads one float4 from each endpoint row, 4 MACs,
// then 16-lane butterfly reduce.
__global__ void edge_dot_kernel(const int* __restrict__ ia, const int* __restrict__ ib, int m,
                                const float4* __restrict__ z24, float* __restrict__ out) {
    int t = blockIdx.x * blockDim.x + threadIdx.x;
    int e = t >> 4, l = t & 15;
    if (e >= m) return;
    int a = ia[e], b = ib[e];
    float4 va = z24[(size_t)a * 16 + l];
    float4 vb = z24[(size_t)b * 16 + l];
    float p = va.x * vb.x + va.y * vb.y + va.z * vb.z + va.w * vb.w;
    p += __shfl_xor(p, 1);
    p += __shfl_xor(p, 2);
    p += __shfl_xor(p, 4);
    p += __shfl_xor(p, 8);
    if (l == 0) out[e] = p;
}

extern "C" void kernel_launch(void* const* d_in, const int* in_sizes, int n_in,
                              void* d_out, int out_size, void* d_ws, size_t ws_size,
                              hipStream_t stream) {
    const float* x    = (const float*)d_in[0];
    const int*   tei  = (const int*)d_in[1];
    const int*   tpos = (const int*)d_in[2];
    const int*   tneg = (const int*)d_in[3];
    const float* W1   = (const float*)d_in[4];
    const float* b1   = (const float*)d_in[5];
    const float* W2   = (const float*)d_in[6];
    const float* b2   = (const float*)d_in[7];
    float* out = (float*)d_out;

    int n  = in_sizes[0] / 256;   // 100000 nodes
    int E  = in_sizes[1] / 2;     // 3.2M train edges
    int ET = in_sizes[2] / 2;     // 500K test edges each
    int nb = (n + 255) / 256;     // 391 scan blocks

    // workspace layout (all 4-byte elems)
    char* w = (char*)d_ws;
    int*   counts = (int*)w;                    w += (size_t)n * 4;
    int*   rowptr = (int*)w;                    w += (size_t)n * 4;
    int*   cursor = (int*)w;                    w += (size_t)n * 4;
    int*   bsum   = (int*)w;                    w += 512 * 4;
    float* dinv   = (float*)w;                  w += (size_t)n * 4;
    float* hs     = (float*)w;                  w += (size_t)16 * n * 4;
    float* gs     = (float*)w;                  w += (size_t)16 * n * 4;
    float* u      = (float*)w;                  w += (size_t)16 * n * 4;
    float* z2     = (float*)w;                  w += (size_t)64 * n * 4;
    int*   eidx   = (int*)w;                    w += (size_t)E * 4;

    hipMemsetAsync(counts, 0, (size_t)n * 4, stream);

    const int* src = tei;
    const int* dst = tei + E;

    hist_kernel<<<(E + 255) / 256, 256, 0, stream>>>(dst, E, counts);
    blocksum_kernel<<<nb, 256, 0, stream>>>(counts, n, bsum);
    scanb_kernel<<<1, 512, 0, stream>>>(bsum, nb);
    scatter_prep_kernel<<<nb, 256, 0, stream>>>(counts, bsum, n, rowptr, cursor, dinv);
    fill_kernel<<<(E + 255) / 256, 256, 0, stream>>>(src, dst, E, cursor, eidx);

    gemm1_kernel<<<(n + 255) / 256, 256, 0, stream>>>(x, W1, dinv, hs, n);
    agg1_kernel<<<(4 * n + 255) / 256, 256, 0, stream>>>(rowptr, counts, eidx,
                                                         (const float4*)hs, dinv, b1,
                                                         (float4*)gs, n);
    agg2_kernel<<<(4 * n + 255) / 256, 256, 0, stream>>>(rowptr, counts, eidx,
                                                         (const float4*)gs, dinv,
                                                         (float4*)u, n);
    gemm2_kernel<<<(4 * n + 255) / 256, 256, 0, stream>>>(u, W2, b2, z2, n);
    edge_dot_kernel<<<(16 * ET + 255) / 256, 256, 0, stream>>>(tpos, tpos + ET, ET,
                                                               (const float4*)z2, out);
    edge_dot_kernel<<<(16 * ET + 255) / 256, 256, 0, stream>>>(tneg, tneg + ET, ET,
                                                               (const float4*)z2, out + ET);
}

// Round 4
// 767.078 us; speedup vs baseline: 2.2330x; 1.0160x over previous
//
#include <hip/hip_runtime.h>

// ---------------------------------------------------------------------------
// 2-layer GCN + link-prediction dot products.
// R4 = R3 + missing __syncthreads() in fill_local_kernel (rowptr reads of lcur
// raced with placement atomicAdds from other waves).
//
// CSR build via binned counting sort:
//   histB  : count per (bucket=dst>>5, replica=blockIdx&7)   [25K counters]
//   scan   : hierarchical exclusive scan of the 25K counts
//   passA  : append packed (src | dlow<<20) to (bucket,replica) tails
//   fill_local: 1 block per 32-node bucket; regs-buffered in-place placement
//            via 32-entry LDS hist/scan/cursors; also emits rowptr/counts/dinv
//
// hs = (x@W1) * dinv
// gs = relu(dinv*(gather(hs)+hs)+b1) * dinv
// u  = dinv*(gather(gs)+gs)
// z2 = u @ W2 + b2
// logits[e] = dot(z2[a], z2[b])
// ---------------------------------------------------------------------------

__global__ void histB_kernel(const int* __restrict__ dst, int E, int* __restrict__ hist2) {
    int e = blockIdx.x * blockDim.x + threadIdx.x;
    if (e >= E) return;
    int d = dst[e];
    atomicAdd(&hist2[((d >> 5) << 3) | (blockIdx.x & 7)], 1);
}

// per-256-block sums
__global__ void blocksum_kernel(const int* __restrict__ v, int m, int* __restrict__ bsum) {
    __shared__ int s[256];
    int i = blockIdx.x * 256 + threadIdx.x;
    s[threadIdx.x] = (i < m) ? v[i] : 0;
    __syncthreads();
    for (int off = 128; off > 0; off >>= 1) {
        if (threadIdx.x < off) s[threadIdx.x] += s[threadIdx.x + off];
        __syncthreads();
    }
    if (threadIdx.x == 0) bsum[blockIdx.x] = s[0];
}

// single-block exclusive scan of bsum[0..nb) (nb <= 512)
__global__ void scanb_kernel(int* __restrict__ bsum, int nb) {
    __shared__ int s[512];
    int t = threadIdx.x;
    int v = (t < nb) ? bsum[t] : 0;
    s[t] = v;
    __syncthreads();
    for (int off = 1; off < 512; off <<= 1) {
        int x = (t >= off) ? s[t - off] : 0;
        __syncthreads();
        s[t] += x;
        __syncthreads();
    }
    if (t < nb) bsum[t] = s[t] - v;   // exclusive
}

// apply: per-chunk exclusive scan + block offset -> cur2; bucket starts -> bstart
__global__ void prep2_kernel(const int* __restrict__ hist2, const int* __restrict__ bsum,
                             int m, int* __restrict__ cur2, int* __restrict__ bstart,
                             int nbk) {
    __shared__ int s[256];
    int t = threadIdx.x;
    int i = blockIdx.x * 256 + t;
    int c = (i < m) ? hist2[i] : 0;
    s[t] = c;
    __syncthreads();
    for (int off = 1; off < 256; off <<= 1) {
        int x = (t >= off) ? s[t - off] : 0;
        __syncthreads();
        s[t] += x;
        __syncthreads();
    }
    if (i < m) {
        int excl = s[t] - c + bsum[blockIdx.x];
        cur2[i] = excl;
        if ((i & 7) == 0) bstart[i >> 3] = excl;
        if (i == m - 1) bstart[nbk] = excl + c;
    }
}

// append packed records to per-(bucket,replica) tails
__global__ void passA_kernel(const int* __restrict__ src, const int* __restrict__ dst, int E,
                             int* __restrict__ cur2, unsigned* __restrict__ tmp) {
    int e = blockIdx.x * blockDim.x + threadIdx.x;
    if (e >= E) return;
    int s = src[e], d = dst[e];
    int slot = atomicAdd(&cur2[((d >> 5) << 3) | (blockIdx.x & 7)], 1);
    tmp[slot] = (unsigned)s | ((unsigned)(d & 31) << 20);
}

// one block per 32-node bucket: in-place local placement + rowptr/counts/dinv
__global__ void fill_local_kernel(const int* __restrict__ bstart, unsigned* __restrict__ tmp,
                                  int* __restrict__ rowptr, int* __restrict__ counts,
                                  float* __restrict__ dinv, int n) {
    int b = blockIdx.x;
    int vb = b << 5;
    int beg = bstart[b], end = bstart[b + 1];
    int t = threadIdx.x;
    __shared__ int lhist[32];
    __shared__ int lcur[32];
    if (t < 32) lhist[t] = 0;
    __syncthreads();
    unsigned r0 = 0xFFFFFFFFu, r1 = 0xFFFFFFFFu, r2 = 0xFFFFFFFFu, r3 = 0xFFFFFFFFu;
    unsigned r4 = 0xFFFFFFFFu, r5 = 0xFFFFFFFFu, r6 = 0xFFFFFFFFu, r7 = 0xFFFFFFFFu;
    {
        int i = beg + t;
        if (i < end) { r0 = tmp[i]; atomicAdd(&lhist[r0 >> 20], 1); } i += 256;
        if (i < end) { r1 = tmp[i]; atomicAdd(&lhist[r1 >> 20], 1); } i += 256;
        if (i < end) { r2 = tmp[i]; atomicAdd(&lhist[r2 >> 20], 1); } i += 256;
        if (i < end) { r3 = tmp[i]; atomicAdd(&lhist[r3 >> 20], 1); } i += 256;
        if (i < end) { r4 = tmp[i]; atomicAdd(&lhist[r4 >> 20], 1); } i += 256;
        if (i < end) { r5 = tmp[i]; atomicAdd(&lhist[r5 >> 20], 1); } i += 256;
        if (i < end) { r6 = tmp[i]; atomicAdd(&lhist[r6 >> 20], 1); } i += 256;
        if (i < end) { r7 = tmp[i]; atomicAdd(&lhist[r7 >> 20], 1); }
    }
    __syncthreads();
    if (t == 0) {
        int run = beg;
        #pragma unroll
        for (int j = 0; j < 32; ++j) { int c = lhist[j]; lcur[j] = run; run += c; }
    }
    __syncthreads();
    if (t < 32 && vb + t < n) {
        int c = lhist[t];
        rowptr[vb + t] = lcur[t];
        counts[vb + t] = c;
        dinv[vb + t]   = rsqrtf((float)c + 1.0f);   // +1: self loop
    }
    __syncthreads();   // R4 FIX: placement atomics below mutate lcur; the
                       // rowptr emission above must finish reading it first.
    int* eidx = (int*)tmp;   // in-place: all reads completed before the barrier
    if (r0 != 0xFFFFFFFFu) { int s = atomicAdd(&lcur[r0 >> 20], 1); eidx[s] = (int)(r0 & 0xFFFFF); }
    if (r1 != 0xFFFFFFFFu) { int s = atomicAdd(&lcur[r1 >> 20], 1); eidx[s] = (int)(r1 & 0xFFFFF); }
    if (r2 != 0xFFFFFFFFu) { int s = atomicAdd(&lcur[r2 >> 20], 1); eidx[s] = (int)(r2 & 0xFFFFF); }
    if (r3 != 0xFFFFFFFFu) { int s = atomicAdd(&lcur[r3 >> 20], 1); eidx[s] = (int)(r3 & 0xFFFFF); }
    if (r4 != 0xFFFFFFFFu) { int s = atomicAdd(&lcur[r4 >> 20], 1); eidx[s] = (int)(r4 & 0xFFFFF); }
    if (r5 != 0xFFFFFFFFu) { int s = atomicAdd(&lcur[r5 >> 20], 1); eidx[s] = (int)(r5 & 0xFFFFF); }
    if (r6 != 0xFFFFFFFFu) { int s = atomicAdd(&lcur[r6 >> 20], 1); eidx[s] = (int)(r6 & 0xFFFFF); }
    if (r7 != 0xFFFFFFFFu) { int s = atomicAdd(&lcur[r7 >> 20], 1); eidx[s] = (int)(r7 & 0xFFFFF); }
}

// hs[row][c] = (sum_k x[row][k] * W1[k][c]) * dinv[row],  c in [0,16)
__global__ void gemm1_kernel(const float* __restrict__ x, const float* __restrict__ W1,
                             const float* __restrict__ dinv, float* __restrict__ hs, int n) {
    __shared__ float4 sW[1024];                   // 256x16 floats
    const float4* W14 = (const float4*)W1;
    for (int i = threadIdx.x; i < 1024; i += 256) sW[i] = W14[i];
    __syncthreads();
    int row = blockIdx.x * 256 + threadIdx.x;
    if (row >= n) return;
    const float4* x4 = (const float4*)(x + (size_t)row * 256);
    float4 a0 = {0,0,0,0}, a1 = {0,0,0,0}, a2 = {0,0,0,0}, a3 = {0,0,0,0};
    for (int k4 = 0; k4 < 64; ++k4) {
        float4 xv = x4[k4];
        #pragma unroll
        for (int j = 0; j < 4; ++j) {
            float xk = (j == 0) ? xv.x : (j == 1) ? xv.y : (j == 2) ? xv.z : xv.w;
            int k = (k4 << 2) + j;
            float4 w0 = sW[k * 4 + 0];
            float4 w1 = sW[k * 4 + 1];
            float4 w2 = sW[k * 4 + 2];
            float4 w3 = sW[k * 4 + 3];
            a0.x += xk * w0.x; a0.y += xk * w0.y; a0.z += xk * w0.z; a0.w += xk * w0.w;
            a1.x += xk * w1.x; a1.y += xk * w1.y; a1.z += xk * w1.z; a1.w += xk * w1.w;
            a2.x += xk * w2.x; a2.y += xk * w2.y; a2.z += xk * w2.z; a2.w += xk * w2.w;
            a3.x += xk * w3.x; a3.y += xk * w3.y; a3.z += xk * w3.z; a3.w += xk * w3.w;
        }
    }
    float di = dinv[row];
    float4* o = (float4*)(hs + (size_t)row * 16);
    a0.x *= di; a0.y *= di; a0.z *= di; a0.w *= di;
    a1.x *= di; a1.y *= di; a1.z *= di; a1.w *= di;
    a2.x *= di; a2.y *= di; a2.z *= di; a2.w *= di;
    a3.x *= di; a3.y *= di; a3.z *= di; a3.w *= di;
    o[0] = a0; o[1] = a1; o[2] = a2; o[3] = a3;
}

// layer-1 aggregate: 4 threads per node, each owns one float4 of the 16 feats.
__global__ void agg1_kernel(const int* __restrict__ rowptr, const int* __restrict__ counts,
                            const int* __restrict__ eidx, const float4* __restrict__ hs4,
                            const float* __restrict__ dinv, const float* __restrict__ b1,
                            float4* __restrict__ gs4, int n) {
    int t = blockIdx.x * blockDim.x + threadIdx.x;
    int v = t >> 2, q = t & 3;
    if (v >= n) return;
    int start = rowptr[v], cnt = counts[v];
    float4 s = {0, 0, 0, 0};
    for (int i = 0; i < cnt; ++i) {
        int sv = eidx[start + i];
        float4 h = hs4[(size_t)sv * 4 + q];
        s.x += h.x; s.y += h.y; s.z += h.z; s.w += h.w;
    }
    float di = dinv[v];
    float4 h = hs4[(size_t)v * 4 + q];
    float4 b = ((const float4*)b1)[q];
    float4 z;
    z.x = fmaxf(di * (s.x + h.x) + b.x, 0.0f) * di;
    z.y = fmaxf(di * (s.y + h.y) + b.y, 0.0f) * di;
    z.z = fmaxf(di * (s.z + h.z) + b.z, 0.0f) * di;
    z.w = fmaxf(di * (s.w + h.w) + b.w, 0.0f) * di;
    gs4[(size_t)v * 4 + q] = z;
}

// layer-2 aggregate: u[v] = dinv*(sum_incoming gs[src] + gs[v])
__global__ void agg2_kernel(const int* __restrict__ rowptr, const int* __restrict__ counts,
                            const int* __restrict__ eidx, const float4* __restrict__ gs4,
                            const float* __restrict__ dinv, float4* __restrict__ u4, int n) {
    int t = blockIdx.x * blockDim.x + threadIdx.x;
    int v = t >> 2, q = t & 3;
    if (v >= n) return;
    int start = rowptr[v], cnt = counts[v];
    float4 s = {0, 0, 0, 0};
    for (int i = 0; i < cnt; ++i) {
        int sv = eidx[start + i];
        float4 g = gs4[(size_t)sv * 4 + q];
        s.x += g.x; s.y += g.y; s.z += g.z; s.w += g.w;
    }
    float di = dinv[v];
    float4 g = gs4[(size_t)v * 4 + q];
    float4 u;
    u.x = di * (s.x + g.x);
    u.y = di * (s.y + g.y);
    u.z = di * (s.z + g.z);
    u.w = di * (s.w + g.w);
    u4[(size_t)v * 4 + q] = u;
}

// z2[v][:] = u[v][:] @ W2 + b2 ; 4 threads per row, each makes 16 of 64 outputs
__global__ void gemm2_kernel(const float* __restrict__ u, const float* __restrict__ W2,
                             const float* __restrict__ b2, float* __restrict__ z2, int n) {
    __shared__ float4 sW[256];                    // 16x64 floats
    __shared__ float sb[64];
    for (int i = threadIdx.x; i < 256; i += 256) sW[i] = ((const float4*)W2)[i];
    if (threadIdx.x < 64) sb[threadIdx.x] = b2[threadIdx.x];
    __syncthreads();
    int t = blockIdx.x * 256 + threadIdx.x;
    int v = t >> 2, jq = t & 3;
    if (v >= n) return;
    const float4* uu4 = (const float4*)(u + (size_t)v * 16);
    float tc[16];
    #pragma unroll
    for (int q = 0; q < 4; ++q) {
        float4 g = uu4[q];
        tc[q * 4 + 0] = g.x;
        tc[q * 4 + 1] = g.y;
        tc[q * 4 + 2] = g.z;
        tc[q * 4 + 3] = g.w;
    }
    float4 o0 = {0,0,0,0}, o1 = {0,0,0,0}, o2 = {0,0,0,0}, o3 = {0,0,0,0};
    #pragma unroll
    for (int c = 0; c < 16; ++c) {
        float tcc = tc[c];
        float4 w0 = sW[c * 16 + jq * 4 + 0];
        float4 w1 = sW[c * 16 + jq * 4 + 1];
        float4 w2 = sW[c * 16 + jq * 4 + 2];
        float4 w3 = sW[c * 16 + jq * 4 + 3];
        o0.x += tcc * w0.x; o0.y += tcc * w0.y; o0.z += tcc * w0.z; o0.w += tcc * w0.w;
        o1.x += tcc * w1.x; o1.y += tcc * w1.y; o1.z += tcc * w1.z; o1.w += tcc * w1.w;
        o2.x += tcc * w2.x; o2.y += tcc * w2.y; o2.z += tcc * w2.z; o2.w += tcc * w2.w;
        o3.x += tcc * w3.x; o3.y += tcc * w3.y; o3.z += tcc * w3.z; o3.w += tcc * w3.w;
    }
    const float4* sb4 = (const float4*)sb;
    float4 b0 = sb4[jq * 4 + 0], b1v = sb4[jq * 4 + 1], b2v = sb4[jq * 4 + 2], b3 = sb4[jq * 4 + 3];
    o0.x += b0.x;  o0.y += b0.y;  o0.z += b0.z;  o0.w += b0.w;
    o1.x += b1v.x; o1.y += b1v.y; o1.z += b1v.z; o1.w += b1v.w;
    o2.x += b2v.x; o2.y += b2v.y; o2.z += b2v.z; o2.w += b2v.w;
    o3.x += b3.x;  o3.y += b3.y;  o3.z += b3.z;  o3.w += b3.w;
    float4* o = (float4*)(z2 + (size_t)v * 64 + jq * 16);
    o[0] = o0; o[1] = o1; o[2] = o2; o[3] = o3;
}

// 16 lanes per edge: lane reads one float4 from each endpoint row, 4 MACs,
// then 16-lane butterfly reduce.
__global__ void edge_dot_kernel(const int* __restrict__ ia, const int* __restrict__ ib, int m,
                                const float4* __restrict__ z24, float* __restrict__ out) {
    int t = blockIdx.x * blockDim.x + threadIdx.x;
    int e = t >> 4, l = t & 15;
    if (e >= m) return;
    int a = ia[e], b = ib[e];
    float4 va = z24[(size_t)a * 16 + l];
    float4 vb = z24[(size_t)b * 16 + l];
    float p = va.x * vb.x + va.y * vb.y + va.z * vb.z + va.w * vb.w;
    p += __shfl_xor(p, 1);
    p += __shfl_xor(p, 2);
    p += __shfl_xor(p, 4);
    p += __shfl_xor(p, 8);
    if (l == 0) out[e] = p;
}

extern "C" void kernel_launch(void* const* d_in, const int* in_sizes, int n_in,
                              void* d_out, int out_size, void* d_ws, size_t ws_size,
                              hipStream_t stream) {
    const float* x    = (const float*)d_in[0];
    const int*   tei  = (const int*)d_in[1];
    const int*   tpos = (const int*)d_in[2];
    const int*   tneg = (const int*)d_in[3];
    const float* W1   = (const float*)d_in[4];
    const float* b1   = (const float*)d_in[5];
    const float* W2   = (const float*)d_in[6];
    const float* b2   = (const float*)d_in[7];
    float* out = (float*)d_out;

    int n   = in_sizes[0] / 256;    // 100000 nodes
    int E   = in_sizes[1] / 2;      // 3.2M train edges
    int ET  = in_sizes[2] / 2;      // 500K test edges each
    int nbk = (n + 31) / 32;        // 3125 buckets
    int m   = nbk * 8;              // 25000 (bucket, replica) counters
    int nb2 = (m + 255) / 256;      // 98 scan chunks

    // workspace layout (all 4-byte elems)
    char* w = (char*)d_ws;
    int*   hist2  = (int*)w;        w += (size_t)m * 4;
    int*   cur2   = (int*)w;        w += (size_t)m * 4;
    int*   bstart = (int*)w;        w += (size_t)(nbk + 1) * 4;
    int*   bsum   = (int*)w;        w += 512 * 4;
    int*   rowptr = (int*)w;        w += (size_t)n * 4;
    int*   counts = (int*)w;        w += (size_t)n * 4;
    float* dinv   = (float*)w;      w += (size_t)n * 4;
    float* hs     = (float*)w;      w += (size_t)16 * n * 4;
    float* gs     = (float*)w;      w += (size_t)16 * n * 4;
    float* u      = (float*)w;      w += (size_t)16 * n * 4;
    float* z2     = (float*)w;      w += (size_t)64 * n * 4;
    unsigned* tmp = (unsigned*)w;   w += (size_t)E * 4;   // records, then eidx in place

    hipMemsetAsync(hist2, 0, (size_t)m * 4, stream);

    const int* src = tei;
    const int* dst = tei + E;

    histB_kernel<<<(E + 255) / 256, 256, 0, stream>>>(dst, E, hist2);
    blocksum_kernel<<<nb2, 256, 0, stream>>>(hist2, m, bsum);
    scanb_kernel<<<1, 512, 0, stream>>>(bsum, nb2);
    prep2_kernel<<<nb2, 256, 0, stream>>>(hist2, bsum, m, cur2, bstart, nbk);
    passA_kernel<<<(E + 255) / 256, 256, 0, stream>>>(src, dst, E, cur2, tmp);
    fill_local_kernel<<<nbk, 256, 0, stream>>>(bstart, tmp, rowptr, counts, dinv, n);

    const int* eidx = (const int*)tmp;
    gemm1_kernel<<<(n + 255) / 256, 256, 0, stream>>>(x, W1, dinv, hs, n);
    agg1_kernel<<<(4 * n + 255) / 256, 256, 0, stream>>>(rowptr, counts, eidx,
                                                         (const float4*)hs, dinv, b1,
                                                         (float4*)gs, n);
    agg2_kernel<<<(4 * n + 255) / 256, 256, 0, stream>>>(rowptr, counts, eidx,
                                                         (const float4*)gs, dinv,
                                                         (float4*)u, n);
    gemm2_kernel<<<(4 * n + 255) / 256, 256, 0, stream>>>(u, W2, b2, z2, n);
    edge_dot_kernel<<<(16 * ET + 255) / 256, 256, 0, stream>>>(tpos, tpos + ET, ET,
                                                               (const float4*)z2, out);
    edge_dot_kernel<<<(16 * ET + 255) / 256, 256, 0, stream>>>(tneg, tneg + ET, ET,
                                                               (const float4*)z2, out + ET);
}

// Round 5
// 454.823 us; speedup vs baseline: 3.7660x; 1.6865x over previous
//
#include <hip/hip_runtime.h>

// ---------------------------------------------------------------------------
// 2-layer GCN + link-prediction dot products.
// R5: CSR build rewritten as over-allocated 2-level LDS-staged bin sort.
//   R4's passA wrote 116 MB HBM (isolated 4B stores to 3125 scattered tails).
//   Now: 196 coarse buckets (512 nodes), CAP-padded regions (no prefix scans),
//   passA1 stages a 4096-edge chunk in LDS/regs, reserves one range per
//   (block,bucket) with a single returning atomic, writes ~84B dense runs.
//   fill2 (1 block/bucket) streams its ~16K records twice (L2-hot) with a
//   512-entry LDS hist/scan/cursor -> eidx + rowptr/counts/dinv.
//
// hs = (x@W1) * dinv
// gs = relu(dinv*(gather(hs)+hs)+b1) * dinv
// u  = dinv*(gather(gs)+gs)
// z2 = u @ W2 + b2          (tmp aliases z2's space; dead before gemm2)
// logits[e] = dot(z2[a], z2[b])
// ---------------------------------------------------------------------------

#define CAP   18432   // slots per coarse bucket (mean 16384, +16 sigma)
#define CHUNK 4096    // edges per passA1 block

__global__ void seed_kernel(int* __restrict__ gtail, int nb1) {
    int t = blockIdx.x * blockDim.x + threadIdx.x;
    if (t < nb1) gtail[t] = t * CAP;
}

// one block per CHUNK of edges: LDS-staged grouped append into bucket regions
__global__ void passA1_kernel(const int* __restrict__ src, const int* __restrict__ dst, int E,
                              int* __restrict__ gtail, unsigned* __restrict__ tmp, int nb1) {
    __shared__ int cnt[256];
    __shared__ int base[256];
    int t = threadIdx.x;
    int c0 = blockIdx.x * CHUNK;
    if (t < nb1) cnt[t] = 0;
    __syncthreads();
    unsigned rec[16];   // (src | dlow<<20), static-indexed -> stays in VGPRs
    unsigned brk[16];   // (bucket<<16 | rank)
    #pragma unroll
    for (int j = 0; j < 16; ++j) {
        int e = c0 + t + j * 256;
        if (e < E) {
            int s = src[e], d = dst[e];
            int b = d >> 9;
            int r = atomicAdd(&cnt[b], 1);
            rec[j] = (unsigned)s | ((unsigned)(d & 511) << 20);
            brk[j] = ((unsigned)b << 16) | (unsigned)r;
        }
    }
    __syncthreads();
    if (t < nb1) base[t] = atomicAdd(&gtail[t], cnt[t]);
    __syncthreads();
    #pragma unroll
    for (int j = 0; j < 16; ++j) {
        int e = c0 + t + j * 256;
        if (e < E) {
            int b = (int)(brk[j] >> 16), r = (int)(brk[j] & 0xFFFFu);
            tmp[base[b] + r] = rec[j];
        }
    }
}

// one block per coarse bucket: stream records twice; 512-entry LDS hist/scan/
// cursors -> eidx placement + rowptr/counts/dinv emission.
__global__ void fill2_kernel(const int* __restrict__ gtail, const unsigned* __restrict__ tmp,
                             int* __restrict__ eidx, int* __restrict__ rowptr,
                             int* __restrict__ counts, float* __restrict__ dinv, int n) {
    int b = blockIdx.x;
    int t = threadIdx.x;
    int beg = b * CAP;
    int cnt_total = gtail[b] - beg;
    __shared__ int h[512];
    __shared__ int cur[512];
    h[t] = 0; h[t + 256] = 0;
    __syncthreads();
    for (int i = t; i < cnt_total; i += 256) {
        unsigned r = tmp[beg + i];
        atomicAdd(&h[r >> 20], 1);
    }
    __syncthreads();
    if (t == 0) {
        int run = beg;
        for (int j = 0; j < 512; ++j) { int c = h[j]; cur[j] = run; run += c; }
    }
    __syncthreads();
    for (int j = t; j < 512; j += 256) {
        int v = (b << 9) + j;
        if (v < n) {
            rowptr[v] = cur[j];
            counts[v] = h[j];
            dinv[v]   = rsqrtf((float)h[j] + 1.0f);   // +1: self loop
        }
    }
    __syncthreads();   // rowptr reads of cur must finish before placement mutates it
    for (int i = t; i < cnt_total; i += 256) {
        unsigned r = tmp[beg + i];
        int p = atomicAdd(&cur[r >> 20], 1);
        eidx[p] = (int)(r & 0xFFFFF);
    }
}

// hs[row][c] = (sum_k x[row][k] * W1[k][c]) * dinv[row],  c in [0,16)
__global__ void gemm1_kernel(const float* __restrict__ x, const float* __restrict__ W1,
                             const float* __restrict__ dinv, float* __restrict__ hs, int n) {
    __shared__ float4 sW[1024];                   // 256x16 floats
    const float4* W14 = (const float4*)W1;
    for (int i = threadIdx.x; i < 1024; i += 256) sW[i] = W14[i];
    __syncthreads();
    int row = blockIdx.x * 256 + threadIdx.x;
    if (row >= n) return;
    const float4* x4 = (const float4*)(x + (size_t)row * 256);
    float4 a0 = {0,0,0,0}, a1 = {0,0,0,0}, a2 = {0,0,0,0}, a3 = {0,0,0,0};
    for (int k4 = 0; k4 < 64; ++k4) {
        float4 xv = x4[k4];
        #pragma unroll
        for (int j = 0; j < 4; ++j) {
            float xk = (j == 0) ? xv.x : (j == 1) ? xv.y : (j == 2) ? xv.z : xv.w;
            int k = (k4 << 2) + j;
            float4 w0 = sW[k * 4 + 0];
            float4 w1 = sW[k * 4 + 1];
            float4 w2 = sW[k * 4 + 2];
            float4 w3 = sW[k * 4 + 3];
            a0.x += xk * w0.x; a0.y += xk * w0.y; a0.z += xk * w0.z; a0.w += xk * w0.w;
            a1.x += xk * w1.x; a1.y += xk * w1.y; a1.z += xk * w1.z; a1.w += xk * w1.w;
            a2.x += xk * w2.x; a2.y += xk * w2.y; a2.z += xk * w2.z; a2.w += xk * w2.w;
            a3.x += xk * w3.x; a3.y += xk * w3.y; a3.z += xk * w3.z; a3.w += xk * w3.w;
        }
    }
    float di = dinv[row];
    float4* o = (float4*)(hs + (size_t)row * 16);
    a0.x *= di; a0.y *= di; a0.z *= di; a0.w *= di;
    a1.x *= di; a1.y *= di; a1.z *= di; a1.w *= di;
    a2.x *= di; a2.y *= di; a2.z *= di; a2.w *= di;
    a3.x *= di; a3.y *= di; a3.z *= di; a3.w *= di;
    o[0] = a0; o[1] = a1; o[2] = a2; o[3] = a3;
}

// layer-1 aggregate: 4 threads per node, each owns one float4 of the 16 feats.
__global__ void agg1_kernel(const int* __restrict__ rowptr, const int* __restrict__ counts,
                            const int* __restrict__ eidx, const float4* __restrict__ hs4,
                            const float* __restrict__ dinv, const float* __restrict__ b1,
                            float4* __restrict__ gs4, int n) {
    int t = blockIdx.x * blockDim.x + threadIdx.x;
    int v = t >> 2, q = t & 3;
    if (v >= n) return;
    int start = rowptr[v], cnt = counts[v];
    float4 s = {0, 0, 0, 0};
    for (int i = 0; i < cnt; ++i) {
        int sv = eidx[start + i];
        float4 h = hs4[(size_t)sv * 4 + q];
        s.x += h.x; s.y += h.y; s.z += h.z; s.w += h.w;
    }
    float di = dinv[v];
    float4 h = hs4[(size_t)v * 4 + q];
    float4 b = ((const float4*)b1)[q];
    float4 z;
    z.x = fmaxf(di * (s.x + h.x) + b.x, 0.0f) * di;
    z.y = fmaxf(di * (s.y + h.y) + b.y, 0.0f) * di;
    z.z = fmaxf(di * (s.z + h.z) + b.z, 0.0f) * di;
    z.w = fmaxf(di * (s.w + h.w) + b.w, 0.0f) * di;
    gs4[(size_t)v * 4 + q] = z;
}

// layer-2 aggregate: u[v] = dinv*(sum_incoming gs[src] + gs[v])
__global__ void agg2_kernel(const int* __restrict__ rowptr, const int* __restrict__ counts,
                            const int* __restrict__ eidx, const float4* __restrict__ gs4,
                            const float* __restrict__ dinv, float4* __restrict__ u4, int n) {
    int t = blockIdx.x * blockDim.x + threadIdx.x;
    int v = t >> 2, q = t & 3;
    if (v >= n) return;
    int start = rowptr[v], cnt = counts[v];
    float4 s = {0, 0, 0, 0};
    for (int i = 0; i < cnt; ++i) {
        int sv = eidx[start + i];
        float4 g = gs4[(size_t)sv * 4 + q];
        s.x += g.x; s.y += g.y; s.z += g.z; s.w += g.w;
    }
    float di = dinv[v];
    float4 g = gs4[(size_t)v * 4 + q];
    float4 u;
    u.x = di * (s.x + g.x);
    u.y = di * (s.y + g.y);
    u.z = di * (s.z + g.z);
    u.w = di * (s.w + g.w);
    u4[(size_t)v * 4 + q] = u;
}

// z2[v][:] = u[v][:] @ W2 + b2 ; 4 threads per row, each makes 16 of 64 outputs
__global__ void gemm2_kernel(const float* __restrict__ u, const float* __restrict__ W2,
                             const float* __restrict__ b2, float* __restrict__ z2, int n) {
    __shared__ float4 sW[256];                    // 16x64 floats
    __shared__ float sb[64];
    for (int i = threadIdx.x; i < 256; i += 256) sW[i] = ((const float4*)W2)[i];
    if (threadIdx.x < 64) sb[threadIdx.x] = b2[threadIdx.x];
    __syncthreads();
    int t = blockIdx.x * 256 + threadIdx.x;
    int v = t >> 2, jq = t & 3;
    if (v >= n) return;
    const float4* uu4 = (const float4*)(u + (size_t)v * 16);
    float tc[16];
    #pragma unroll
    for (int q = 0; q < 4; ++q) {
        float4 g = uu4[q];
        tc[q * 4 + 0] = g.x;
        tc[q * 4 + 1] = g.y;
        tc[q * 4 + 2] = g.z;
        tc[q * 4 + 3] = g.w;
    }
    float4 o0 = {0,0,0,0}, o1 = {0,0,0,0}, o2 = {0,0,0,0}, o3 = {0,0,0,0};
    #pragma unroll
    for (int c = 0; c < 16; ++c) {
        float tcc = tc[c];
        float4 w0 = sW[c * 16 + jq * 4 + 0];
        float4 w1 = sW[c * 16 + jq * 4 + 1];
        float4 w2 = sW[c * 16 + jq * 4 + 2];
        float4 w3 = sW[c * 16 + jq * 4 + 3];
        o0.x += tcc * w0.x; o0.y += tcc * w0.y; o0.z += tcc * w0.z; o0.w += tcc * w0.w;
        o1.x += tcc * w1.x; o1.y += tcc * w1.y; o1.z += tcc * w1.z; o1.w += tcc * w1.w;
        o2.x += tcc * w2.x; o2.y += tcc * w2.y; o2.z += tcc * w2.z; o2.w += tcc * w2.w;
        o3.x += tcc * w3.x; o3.y += tcc * w3.y; o3.z += tcc * w3.z; o3.w += tcc * w3.w;
    }
    const float4* sb4 = (const float4*)sb;
    float4 b0 = sb4[jq * 4 + 0], b1v = sb4[jq * 4 + 1], b2v = sb4[jq * 4 + 2], b3 = sb4[jq * 4 + 3];
    o0.x += b0.x;  o0.y += b0.y;  o0.z += b0.z;  o0.w += b0.w;
    o1.x += b1v.x; o1.y += b1v.y; o1.z += b1v.z; o1.w += b1v.w;
    o2.x += b2v.x; o2.y += b2v.y; o2.z += b2v.z; o2.w += b2v.w;
    o3.x += b3.x;  o3.y += b3.y;  o3.z += b3.z;  o3.w += b3.w;
    float4* o = (float4*)(z2 + (size_t)v * 64 + jq * 16);
    o[0] = o0; o[1] = o1; o[2] = o2; o[3] = o3;
}

// 16 lanes per edge: lane reads one float4 from each endpoint row, 4 MACs,
// then 16-lane butterfly reduce.
__global__ void edge_dot_kernel(const int* __restrict__ ia, const int* __restrict__ ib, int m,
                                const float4* __restrict__ z24, float* __restrict__ out) {
    int t = blockIdx.x * blockDim.x + threadIdx.x;
    int e = t >> 4, l = t & 15;
    if (e >= m) return;
    int a = ia[e], b = ib[e];
    float4 va = z24[(size_t)a * 16 + l];
    float4 vb = z24[(size_t)b * 16 + l];
    float p = va.x * vb.x + va.y * vb.y + va.z * vb.z + va.w * vb.w;
    p += __shfl_xor(p, 1);
    p += __shfl_xor(p, 2);
    p += __shfl_xor(p, 4);
    p += __shfl_xor(p, 8);
    if (l == 0) out[e] = p;
}

extern "C" void kernel_launch(void* const* d_in, const int* in_sizes, int n_in,
                              void* d_out, int out_size, void* d_ws, size_t ws_size,
                              hipStream_t stream) {
    const float* x    = (const float*)d_in[0];
    const int*   tei  = (const int*)d_in[1];
    const int*   tpos = (const int*)d_in[2];
    const int*   tneg = (const int*)d_in[3];
    const float* W1   = (const float*)d_in[4];
    const float* b1   = (const float*)d_in[5];
    const float* W2   = (const float*)d_in[6];
    const float* b2   = (const float*)d_in[7];
    float* out = (float*)d_out;

    int n   = in_sizes[0] / 256;    // 100000 nodes
    int E   = in_sizes[1] / 2;      // 3.2M train edges
    int ET  = in_sizes[2] / 2;      // 500K test edges each
    int nb1 = (n + 511) >> 9;       // 196 coarse buckets (<=256 for LDS cnt[])

    // workspace layout (all 4-byte elems)
    char* w = (char*)d_ws;
    int*   gtail  = (int*)w;        w += 256 * 4;
    int*   rowptr = (int*)w;        w += (size_t)n * 4;
    int*   counts = (int*)w;        w += (size_t)n * 4;
    float* dinv   = (float*)w;      w += (size_t)n * 4;
    float* hs     = (float*)w;      w += (size_t)16 * n * 4;
    float* gs     = (float*)w;      w += (size_t)16 * n * 4;
    float* u      = (float*)w;      w += (size_t)16 * n * 4;
    float* z2     = (float*)w;      w += (size_t)64 * n * 4;
    int*   eidx   = (int*)w;        w += (size_t)nb1 * CAP * 4;
    unsigned* tmp = (unsigned*)z2;  // aliases z2: tmp dead before gemm2 writes z2

    const int* src = tei;
    const int* dst = tei + E;

    seed_kernel<<<1, 256, 0, stream>>>(gtail, nb1);
    passA1_kernel<<<(E + CHUNK - 1) / CHUNK, 256, 0, stream>>>(src, dst, E, gtail, tmp, nb1);
    fill2_kernel<<<nb1, 256, 0, stream>>>(gtail, tmp, eidx, rowptr, counts, dinv, n);

    gemm1_kernel<<<(n + 255) / 256, 256, 0, stream>>>(x, W1, dinv, hs, n);
    agg1_kernel<<<(4 * n + 255) / 256, 256, 0, stream>>>(rowptr, counts, eidx,
                                                         (const float4*)hs, dinv, b1,
                                                         (float4*)gs, n);
    agg2_kernel<<<(4 * n + 255) / 256, 256, 0, stream>>>(rowptr, counts, eidx,
                                                         (const float4*)gs, dinv,
                                                         (float4*)u, n);
    gemm2_kernel<<<(4 * n + 255) / 256, 256, 0, stream>>>(u, W2, b2, z2, n);
    edge_dot_kernel<<<(16 * ET + 255) / 256, 256, 0, stream>>>(tpos, tpos + ET, ET,
                                                               (const float4*)z2, out);
    edge_dot_kernel<<<(16 * ET + 255) / 256, 256, 0, stream>>>(tneg, tneg + ET, ET,
                                                               (const float4*)z2, out + ET);
}